// Round 2
// baseline (3159.943 us; speedup 1.0000x reference)
//
#include <hip/hip_runtime.h>
#include <hip/hip_fp16.h>
#include <stdint.h>

typedef _Float16 f16;
typedef _Float16 f16x8 __attribute__((ext_vector_type(8)));
typedef _Float16 f16x4 __attribute__((ext_vector_type(4)));
typedef float    f32x4 __attribute__((ext_vector_type(4)));

#define MFMA16(a, b, c) __builtin_amdgcn_mfma_f32_16x16x32_f16((a), (b), (c), 0, 0, 0)

// ---- problem dims ----
static constexpr int N1P = 1152;   // enc layer-1 N (1056) padded to 9*128

// ---- workspace layout (bytes, all 256-aligned) ----
static constexpr size_t OFF_FLAGS = 0;                                    // 4 KiB flag region
static constexpr size_t OFF_XT    = 4096;                                 // f16 [64][257][1024] (row 0 = zeros = prev at t=0)
static constexpr size_t OFF_WE1T  = OFF_XT   + (size_t)64 * 257 * 1024 * 2;  // f16 [1152][2048]
static constexpr size_t OFF_WE2T  = OFF_WE1T + (size_t)1152 * 2048 * 2;      // f16 [64][1152]
static constexpr size_t OFF_WD1T  = OFF_WE2T + (size_t)64 * 1152 * 2;        // f16 [1056][1088]
static constexpr size_t OFF_WD2T  = OFF_WD1T + (size_t)1056 * 1088 * 2;      // f16 [1024][1056]
static constexpr size_t OFF_HENC  = OFF_WD2T + (size_t)1024 * 1056 * 2;      // f16 [16384][1152]; decoder reuses as hG[256][64][1056]
static constexpr size_t OFF_CTRL  = OFF_HENC + (size_t)16384 * 1152 * 2;     // f16 [256][64][64]
static constexpr size_t OFF_ST    = OFF_CTRL + (size_t)256 * 64 * 64 * 2;    // f16 [256][64][1024] (decoder outputs)
static constexpr size_t OFF_HG    = OFF_ST   + (size_t)256 * 64 * 1024 * 2;  // (legacy, unused)
static constexpr size_t WS_NEED   = OFF_HG   + (size_t)64 * 1056 * 2;

// decoder LDS: Wd1 slice [32][1096] + Wd2 slice [32][1064] + transpose tile [32][36]
static constexpr int SW1S = 1096, SW2S = 1064, STS = 36;
static constexpr size_t DEC_LDS = (size_t)(32 * (SW1S + SW2S) + 32 * STS) * 2;  // 140544

// =============================== prep kernels ===============================

__global__ __launch_bounds__(256) void k_zero_x0(f16* __restrict__ xT) {
  f16x4 z = {};
  *(f16x4*)(xT + (size_t)blockIdx.x * 257 * 1024 + threadIdx.x * 4) = z;
}

// x [64][1024][256] f32  ->  xT[b][t+1][s] f16   (xT row 0 stays zero)
__global__ __launch_bounds__(256) void k_transpose_x(const float* __restrict__ x,
                                                     f16* __restrict__ xT) {
  __shared__ float tile[32][33];
  int b = blockIdx.z, s0 = blockIdx.x * 32, t0 = blockIdx.y * 32;
  int r = threadIdx.x >> 3, c4 = (threadIdx.x & 7) * 4;
  const float4 v = *(const float4*)(x + ((size_t)b * 1024 + s0 + r) * 256 + t0 + c4);
  tile[r][c4 + 0] = v.x; tile[r][c4 + 1] = v.y;
  tile[r][c4 + 2] = v.z; tile[r][c4 + 3] = v.w;
  __syncthreads();
  f16x4 o;
  o[0] = (f16)tile[c4 + 0][r]; o[1] = (f16)tile[c4 + 1][r];
  o[2] = (f16)tile[c4 + 2][r]; o[3] = (f16)tile[c4 + 3][r];
  *(f16x4*)(xT + ((size_t)b * 257 + t0 + r + 1) * 1024 + s0 + c4) = o;
}

// in [K][N] f32 -> out [Npad][Kpad] f16 (zero pad where k>=K or n>=N)
__global__ __launch_bounds__(256) void k_transpose_w(const float* __restrict__ in,
                                                     f16* __restrict__ out,
                                                     int K, int N, int Kpad, int Npad) {
  __shared__ float tile[32][33];
  int k0 = blockIdx.x * 32, n0 = blockIdx.y * 32;
  int r = threadIdx.x >> 3, c4 = (threadIdx.x & 7) * 4;
#pragma unroll
  for (int i = 0; i < 4; i++) {
    int k = k0 + r, n = n0 + c4 + i;
    tile[r][c4 + i] = (k < K && n < N) ? in[(size_t)k * N + n] : 0.f;
  }
  __syncthreads();
  int n = n0 + r;
  if (n < Npad) {
    f16x4 o;
    o[0] = (f16)tile[c4 + 0][r]; o[1] = (f16)tile[c4 + 1][r];
    o[2] = (f16)tile[c4 + 2][r]; o[3] = (f16)tile[c4 + 3][r];
    *(f16x4*)(out + (size_t)n * Kpad + k0 + c4) = o;
  }
}

// =============================== encoder ===============================
__global__ __launch_bounds__(256) void k_enc1(const f16* __restrict__ xT,
                                              const f16* __restrict__ We1T,
                                              const float* __restrict__ be1,
                                              f16* __restrict__ Henc) {
  __shared__ f16 sA[128 * 40];
  __shared__ f16 sB[128 * 40];
  int m0 = blockIdx.x * 128, n0 = blockIdx.y * 128;
  int b = m0 >> 8, t0 = m0 & 255;
  int tid = threadIdx.x, w = tid >> 6, l = tid & 63;
  int wm = (w >> 1) * 64, wn = (w & 1) * 64;
  int lr = l & 15, lq = l >> 4;
  f32x4 acc[4][4] = {};
  for (int kt = 0; kt < 64; kt++) {
    int k0 = kt * 32;
    __syncthreads();
    int tshift = (k0 < 1024) ? 0 : 1;
    int ks = (k0 < 1024) ? k0 : (k0 - 1024);
    int idx = tid;
#pragma unroll
    for (int rep = 0; rep < 2; rep++, idx += 256) {
      int r = idx >> 2, c = idx & 3;
      *(uint4*)(&sA[r * 40 + c * 8]) =
          *(const uint4*)(xT + ((size_t)(b * 257 + t0 + r + tshift)) * 1024 + ks + c * 8);
      *(uint4*)(&sB[r * 40 + c * 8]) =
          *(const uint4*)(We1T + ((size_t)(n0 + r)) * 2048 + k0 + c * 8);
    }
    __syncthreads();
    f16x8 a[4], bb[4];
#pragma unroll
    for (int i = 0; i < 4; i++) a[i] = *(const f16x8*)(&sA[(wm + i * 16 + lr) * 40 + lq * 8]);
#pragma unroll
    for (int j = 0; j < 4; j++) bb[j] = *(const f16x8*)(&sB[(wn + j * 16 + lr) * 40 + lq * 8]);
#pragma unroll
    for (int i = 0; i < 4; i++)
#pragma unroll
      for (int j = 0; j < 4; j++) acc[i][j] = MFMA16(a[i], bb[j], acc[i][j]);
  }
#pragma unroll
  for (int j = 0; j < 4; j++) {
    int n = n0 + wn + j * 16 + lr;
    float bias = (n < 1056) ? be1[n] : 0.f;
#pragma unroll
    for (int i = 0; i < 4; i++) {
#pragma unroll
      for (int rr = 0; rr < 4; rr++) {
        int m = m0 + wm + i * 16 + lq * 4 + rr;
        float v = acc[i][j][rr] + bias;
        v = v > 0.f ? v : 0.f;
        Henc[(size_t)m * N1P + n] = (f16)v;
      }
    }
  }
}

__global__ __launch_bounds__(256) void k_enc2(const f16* __restrict__ Henc,
                                              const f16* __restrict__ We2T,
                                              const float* __restrict__ be2,
                                              f16* __restrict__ ctrl) {
  __shared__ f16 sA[128 * 40];
  __shared__ f16 sB[64 * 40];
  int m0 = blockIdx.x * 128;
  int tid = threadIdx.x, w = tid >> 6, l = tid & 63;
  int wm = w * 32;
  int lr = l & 15, lq = l >> 4;
  f32x4 acc[2][4] = {};
  for (int kt = 0; kt < 36; kt++) {
    int k0 = kt * 32;
    __syncthreads();
    int idx = tid;
#pragma unroll
    for (int rep = 0; rep < 2; rep++, idx += 256) {
      int r = idx >> 2, c = idx & 3;
      *(uint4*)(&sA[r * 40 + c * 8]) =
          *(const uint4*)(Henc + (size_t)(m0 + r) * N1P + k0 + c * 8);
    }
    {
      int r = tid >> 2, c = tid & 3;
      *(uint4*)(&sB[r * 40 + c * 8]) =
          *(const uint4*)(We2T + (size_t)r * N1P + k0 + c * 8);
    }
    __syncthreads();
    f16x8 a[2], bb[4];
#pragma unroll
    for (int i = 0; i < 2; i++) a[i] = *(const f16x8*)(&sA[(wm + i * 16 + lr) * 40 + lq * 8]);
#pragma unroll
    for (int j = 0; j < 4; j++) bb[j] = *(const f16x8*)(&sB[(j * 16 + lr) * 40 + lq * 8]);
#pragma unroll
    for (int i = 0; i < 2; i++)
#pragma unroll
      for (int j = 0; j < 4; j++) acc[i][j] = MFMA16(a[i], bb[j], acc[i][j]);
  }
#pragma unroll
  for (int j = 0; j < 4; j++) {
    int n = j * 16 + lr;
    float bias = be2[n];
#pragma unroll
    for (int i = 0; i < 2; i++) {
#pragma unroll
      for (int rr = 0; rr < 4; rr++) {
        int m = m0 + wm + i * 16 + lq * 4 + rr;
        int bb_ = m >> 8, t = m & 255;
        ctrl[((size_t)t * 64 + bb_) * 64 + n] = (f16)(acc[i][j][rr] + bias);
      }
    }
  }
}

// =============================== decoder ===============================
// Write-through stores: bypass L1/L2, land at the device coherence point
// (MALL) -> no release fence (buffer_wbl2) ever needed.
__device__ __forceinline__ void st_u64_wt(void* p, uint64_t v) {
  asm volatile("global_store_dwordx2 %0, %1, off sc0 sc1" :: "v"(p), "v"(v) : "memory");
}
__device__ __forceinline__ void st_u16_wt(void* p, unsigned v) {
  asm volatile("global_store_short %0, %1, off sc0 sc1" :: "v"(p), "v"(v) : "memory");
}
__device__ __forceinline__ uint64_t ld_flag(const uint64_t* p) {
  return __hip_atomic_load(p, __ATOMIC_RELAXED, __HIP_MEMORY_SCOPE_AGENT);
}

// grid = 66 blocks: 2 groups (32 batch rows each) x 33 column-slice blocks.
// Fence-free exchange with versioned per-producer flags (NO atomic RMWs):
// producer j write-through-stores its data tile (coalesced dwordx2 via LDS
// transpose), waits vmcnt(0)+syncthreads, then ONE fire-and-forget u16 WT
// store flag[j] = t+1. Consumers poll 4x u64 relaxed agent loads of the flag
// line and compare to the replicated version pattern -> zero RMW contention.
// Data loads stay plain cached loads: every exchanged address is t-indexed,
// touched at most once per dispatch (first-touch-after-flag).
// Flag region per group (base + g*256): [0..63] hflag u16[32] (j=0..31),
// [64..71] hflag u16 for j=32, [128..191] sflag u16[32].
__global__ __launch_bounds__(256, 1) void k_decoder(
    const f16* __restrict__ ctrl, const f16* __restrict__ Wd1T,
    const f16* __restrict__ Wd2T, const float* __restrict__ bd1,
    const float* __restrict__ bd2, f16* __restrict__ states,
    f16* __restrict__ hG, unsigned* __restrict__ flags) {
  extern __shared__ f16 smem[];
  f16* sW1 = smem;
  f16* sW2 = smem + 32 * SW1S;
  f16* sT  = smem + 32 * (SW1S + SW2S);   // [32][STS] transpose tile
  int blk = blockIdx.x;
  int g = blk / 33, j = blk % 33;
  int r0 = g * 32, n0 = j * 32;
  int tid = threadIdx.x, w = tid >> 6, l = tid & 63;
  int lr = l & 15, lq = l >> 4;
  int mt = w >> 1, nt = w & 1;

  // pin weight column-slices in LDS
  for (int idx = tid; idx < 32 * 136; idx += 256) {
    int c = idx / 136, q = idx % 136;
    *(uint4*)(&sW1[c * SW1S + q * 8]) = *(const uint4*)(Wd1T + (size_t)(n0 + c) * 1088 + q * 8);
  }
  if (j < 32) {
    for (int idx = tid; idx < 32 * 132; idx += 256) {
      int c = idx / 132, q = idx % 132;
      *(uint4*)(&sW2[c * SW2S + q * 8]) = *(const uint4*)(Wd2T + (size_t)(n0 + c) * 1056 + q * 8);
    }
  }
  __syncthreads();

  char* fb = (char*)flags + (size_t)g * 256;
  const uint64_t* hfA = (const uint64_t*)fb;          // 4x u64: hflag[0..31]
  const uint64_t* hfB = (const uint64_t*)(fb + 64);   // low u16 = hflag[32]
  const uint64_t* sfA = (const uint64_t*)(fb + 128);  // 4x u64: sflag[0..31]
  char* hf_me = (j < 32) ? (fb + j * 2) : (fb + 64);
  char* sf_me = fb + 128 + j * 2;

  int row_b = r0 + mt * 16 + lr;     // this lane's A row (global batch index)
  int wrow = nt * 16 + lr;           // this lane's B column (local)
  float bias1 = bd1[n0 + wrow];
  float bias2 = (j < 32) ? bd2[n0 + wrow] : 0.f;
  int orow = tid >> 3, oseg = tid & 7;  // coalesced-store assignment (8B each)

  for (int t = 0; t < 256; t++) {
    // ---- GEMM1: h_slice = relu(inp @ Wd1_slice + bd1) ----
    // ctrl part has no cross-step dependency: issue before the wait.
    f32x4 acc[4] = {};
    const f16* ctrlRow = ctrl + ((size_t)t * 64 + row_b) * 64;
    {
      f16x8 a0 = *(const f16x8*)(ctrlRow + lq * 8);
      f16x8 b0 = *(const f16x8*)(&sW1[wrow * SW1S + lq * 8]);
      acc[0] = MFMA16(a0, b0, acc[0]);
      f16x8 a1 = *(const f16x8*)(ctrlRow + 32 + lq * 8);
      f16x8 b1 = *(const f16x8*)(&sW1[wrow * SW1S + 32 + lq * 8]);
      acc[1] = MFMA16(a1, b1, acc[1]);
    }
    if (t > 0) {
      uint64_t pat = 0x0001000100010001ULL * (uint64_t)t;  // states[t-1] ready
      for (;;) {
        uint64_t a = ld_flag(sfA + 0), b = ld_flag(sfA + 1);
        uint64_t c = ld_flag(sfA + 2), d = ld_flag(sfA + 3);
        if ((((a ^ pat) | (b ^ pat)) | ((c ^ pat) | (d ^ pat))) == 0) break;
        __builtin_amdgcn_s_sleep(1);
      }
      asm volatile("" ::: "memory");  // no data-load hoisting above the poll
      const f16* stateRow = states + ((size_t)(t - 1) * 64 + row_b) * 1024 - 64;
#pragma unroll 8
      for (int kt = 2; kt < 34; kt++) {
        int koff = kt * 32 + lq * 8;
        f16x8 a = *(const f16x8*)(stateRow + koff);
        f16x8 bb = *(const f16x8*)(&sW1[wrow * SW1S + koff]);
        acc[kt & 3] = MFMA16(a, bb, acc[kt & 3]);
      }
    }
    f32x4 r1 = (acc[0] + acc[1]) + (acc[2] + acc[3]);
#pragma unroll
    for (int rr = 0; rr < 4; rr++) {
      float v = r1[rr] + bias1;
      v = v > 0.f ? v : 0.f;
      sT[(mt * 16 + lq * 4 + rr) * STS + nt * 16 + lr] = (f16)v;
    }
    __syncthreads();
    {
      uint64_t d = *(const uint64_t*)(&sT[orow * STS + oseg * 4]);
      st_u64_wt(hG + ((size_t)t * 64 + r0 + orow) * 1056 + n0 + oseg * 4, d);
    }
    asm volatile("s_waitcnt vmcnt(0)" ::: "memory");
    __syncthreads();
    if (tid == 0) st_u16_wt(hf_me, (unsigned)(t + 1));

    // ---- GEMM2: out_slice = h @ Wd2_slice + bd2 ----
    if (j < 32) {
      uint64_t pat = 0x0001000100010001ULL * (uint64_t)(t + 1);  // h[t] ready
      for (;;) {
        uint64_t a = ld_flag(hfA + 0), b = ld_flag(hfA + 1);
        uint64_t c = ld_flag(hfA + 2), d = ld_flag(hfA + 3);
        uint64_t e = ld_flag(hfB);
        if (((((a ^ pat) | (b ^ pat)) | ((c ^ pat) | (d ^ pat))) |
             (e ^ (uint64_t)(t + 1))) == 0) break;
        __builtin_amdgcn_s_sleep(1);
      }
      asm volatile("" ::: "memory");
      f32x4 acc2[4] = {};
      const f16* hRow = hG + ((size_t)t * 64 + row_b) * 1056;
#pragma unroll 8
      for (int kt = 0; kt < 33; kt++) {
        int koff = kt * 32 + lq * 8;
        f16x8 a = *(const f16x8*)(hRow + koff);
        f16x8 bb = *(const f16x8*)(&sW2[wrow * SW2S + koff]);
        acc2[kt & 3] = MFMA16(a, bb, acc2[kt & 3]);
      }
      f32x4 r2 = (acc2[0] + acc2[1]) + (acc2[2] + acc2[3]);
#pragma unroll
      for (int rr = 0; rr < 4; rr++)
        sT[(mt * 16 + lq * 4 + rr) * STS + nt * 16 + lr] = (f16)(r2[rr] + bias2);
      __syncthreads();
      {
        uint64_t d = *(const uint64_t*)(&sT[orow * STS + oseg * 4]);
        st_u64_wt(states + ((size_t)t * 64 + r0 + orow) * 1024 + n0 + oseg * 4, d);
      }
      asm volatile("s_waitcnt vmcnt(0)" ::: "memory");
      __syncthreads();
      if (tid == 0) st_u16_wt(sf_me, (unsigned)(t + 1));
    }
  }
}

// =============================== output ===============================
__global__ __launch_bounds__(256) void k_out(const f16* __restrict__ states,
                                             float* __restrict__ out) {
  __shared__ float tile[32][33];
  int b = blockIdx.z, t0 = blockIdx.x * 32, s0 = blockIdx.y * 32;
  int r = threadIdx.x >> 3, c4 = (threadIdx.x & 7) * 4;
  f16x4 v = *(const f16x4*)(states + ((size_t)(t0 + r) * 64 + b) * 1024 + s0 + c4);
  tile[r][c4 + 0] = (float)v[0]; tile[r][c4 + 1] = (float)v[1];
  tile[r][c4 + 2] = (float)v[2]; tile[r][c4 + 3] = (float)v[3];
  __syncthreads();
  float4 o;
  o.x = tile[c4 + 0][r]; o.y = tile[c4 + 1][r];
  o.z = tile[c4 + 2][r]; o.w = tile[c4 + 3][r];
  *(float4*)(out + ((size_t)b * 1024 + s0 + r) * 256 + t0 + c4) = o;
}

// =============================== launch ===============================

extern "C" void kernel_launch(void* const* d_in, const int* in_sizes, int n_in,
                              void* d_out, int out_size, void* d_ws, size_t ws_size,
                              hipStream_t stream) {
  const float* x   = (const float*)d_in[0];
  const float* We1 = (const float*)d_in[1];
  const float* be1 = (const float*)d_in[2];
  const float* We2 = (const float*)d_in[3];
  const float* be2 = (const float*)d_in[4];
  const float* Wd1 = (const float*)d_in[5];
  const float* bd1 = (const float*)d_in[6];
  const float* Wd2 = (const float*)d_in[7];
  const float* bd2 = (const float*)d_in[8];
  float* outp = (float*)d_out;

  if (ws_size < WS_NEED) return;
  char* ws = (char*)d_ws;
  unsigned* flags = (unsigned*)(ws + OFF_FLAGS);
  f16* xT    = (f16*)(ws + OFF_XT);
  f16* We1T  = (f16*)(ws + OFF_WE1T);
  f16* We2T  = (f16*)(ws + OFF_WE2T);
  f16* Wd1T  = (f16*)(ws + OFF_WD1T);
  f16* Wd2T  = (f16*)(ws + OFF_WD2T);
  f16* Henc  = (f16*)(ws + OFF_HENC);
  f16* ctrl  = (f16*)(ws + OFF_CTRL);
  f16* st    = (f16*)(ws + OFF_ST);
  f16* hG    = Henc;  // decoder h exchange, t-indexed [256][64][1056], aliases Henc (dead after enc2)

  (void)hipMemsetAsync(flags, 0, 4096, stream);
  k_zero_x0<<<64, 256, 0, stream>>>(xT);
  k_transpose_x<<<dim3(32, 8, 64), 256, 0, stream>>>(x, xT);
  k_transpose_w<<<dim3(64, 36), 256, 0, stream>>>(We1, We1T, 2048, 1056, 2048, 1152);
  k_transpose_w<<<dim3(36, 2), 256, 0, stream>>>(We2, We2T, 1056, 64, 1152, 64);
  k_transpose_w<<<dim3(34, 33), 256, 0, stream>>>(Wd1, Wd1T, 1088, 1056, 1088, 1056);
  k_transpose_w<<<dim3(33, 32), 256, 0, stream>>>(Wd2, Wd2T, 1056, 1024, 1056, 1024);
  k_enc1<<<dim3(128, 9), 256, 0, stream>>>(xT, We1T, be1, Henc);
  k_enc2<<<128, 256, 0, stream>>>(Henc, We2T, be2, ctrl);
  (void)hipFuncSetAttribute((const void*)k_decoder, hipFuncAttributeMaxDynamicSharedMemorySize,
                            (int)DEC_LDS);
  k_decoder<<<66, 256, DEC_LDS, stream>>>(ctrl, Wd1T, Wd2T, bd1, bd2, st, hG, flags);
  k_out<<<dim3(8, 32, 64), 256, 0, stream>>>(st, outp);
}

// Round 4
// 3050.198 us; speedup vs baseline: 1.0360x; 1.0360x over previous
//
#include <hip/hip_runtime.h>
#include <hip/hip_fp16.h>
#include <stdint.h>

typedef _Float16 f16;
typedef _Float16 f16x8 __attribute__((ext_vector_type(8)));
typedef _Float16 f16x4 __attribute__((ext_vector_type(4)));
typedef float    f32x4 __attribute__((ext_vector_type(4)));

#define MFMA16(a, b, c) __builtin_amdgcn_mfma_f32_16x16x32_f16((a), (b), (c), 0, 0, 0)

// ---- problem dims ----
static constexpr int N1P = 1152;   // enc layer-1 N (1056) padded to 9*128

// ---- workspace layout (bytes, all 256-aligned) ----
static constexpr size_t OFF_FLAGS = 0;                                    // 4 KiB flag region
static constexpr size_t OFF_XT    = 4096;                                 // f16 [64][257][1024] (row 0 = zeros = prev at t=0)
static constexpr size_t OFF_WE1T  = OFF_XT   + (size_t)64 * 257 * 1024 * 2;  // f16 [1152][2048]
static constexpr size_t OFF_WE2T  = OFF_WE1T + (size_t)1152 * 2048 * 2;      // f16 [64][1152]
static constexpr size_t OFF_WD1T  = OFF_WE2T + (size_t)64 * 1152 * 2;        // f16 [1056][1088]
static constexpr size_t OFF_WD2T  = OFF_WD1T + (size_t)1056 * 1088 * 2;      // f16 [1024][1056]
static constexpr size_t OFF_HENC  = OFF_WD2T + (size_t)1024 * 1056 * 2;      // f16 [16384][1152]; decoder reuses as hG[256][64][1056]
static constexpr size_t OFF_CTRL  = OFF_HENC + (size_t)16384 * 1152 * 2;     // f16 [256][64][64]
static constexpr size_t OFF_ST    = OFF_CTRL + (size_t)256 * 64 * 64 * 2;    // f16 [256][64][1024] (decoder outputs)
static constexpr size_t OFF_HG    = OFF_ST   + (size_t)256 * 64 * 1024 * 2;  // (legacy, unused)
static constexpr size_t WS_NEED   = OFF_HG   + (size_t)64 * 1056 * 2;

// decoder LDS: Wd1 slice [32][1096] + Wd2 slice [32][1064] (padded strides)
static constexpr int SW1S = 1096, SW2S = 1064;
static constexpr size_t DEC_LDS = (size_t)32 * (SW1S + SW2S) * 2;  // 138240

// =============================== prep kernels ===============================

__global__ __launch_bounds__(256) void k_zero_x0(f16* __restrict__ xT) {
  f16x4 z = {};
  *(f16x4*)(xT + (size_t)blockIdx.x * 257 * 1024 + threadIdx.x * 4) = z;
}

// x [64][1024][256] f32  ->  xT[b][t+1][s] f16   (xT row 0 stays zero)
__global__ __launch_bounds__(256) void k_transpose_x(const float* __restrict__ x,
                                                     f16* __restrict__ xT) {
  __shared__ float tile[32][33];
  int b = blockIdx.z, s0 = blockIdx.x * 32, t0 = blockIdx.y * 32;
  int r = threadIdx.x >> 3, c4 = (threadIdx.x & 7) * 4;
  const float4 v = *(const float4*)(x + ((size_t)b * 1024 + s0 + r) * 256 + t0 + c4);
  tile[r][c4 + 0] = v.x; tile[r][c4 + 1] = v.y;
  tile[r][c4 + 2] = v.z; tile[r][c4 + 3] = v.w;
  __syncthreads();
  f16x4 o;
  o[0] = (f16)tile[c4 + 0][r]; o[1] = (f16)tile[c4 + 1][r];
  o[2] = (f16)tile[c4 + 2][r]; o[3] = (f16)tile[c4 + 3][r];
  *(f16x4*)(xT + ((size_t)b * 257 + t0 + r + 1) * 1024 + s0 + c4) = o;
}

// in [K][N] f32 -> out [Npad][Kpad] f16 (zero pad where k>=K or n>=N)
__global__ __launch_bounds__(256) void k_transpose_w(const float* __restrict__ in,
                                                     f16* __restrict__ out,
                                                     int K, int N, int Kpad, int Npad) {
  __shared__ float tile[32][33];
  int k0 = blockIdx.x * 32, n0 = blockIdx.y * 32;
  int r = threadIdx.x >> 3, c4 = (threadIdx.x & 7) * 4;
#pragma unroll
  for (int i = 0; i < 4; i++) {
    int k = k0 + r, n = n0 + c4 + i;
    tile[r][c4 + i] = (k < K && n < N) ? in[(size_t)k * N + n] : 0.f;
  }
  __syncthreads();
  int n = n0 + r;
  if (n < Npad) {
    f16x4 o;
    o[0] = (f16)tile[c4 + 0][r]; o[1] = (f16)tile[c4 + 1][r];
    o[2] = (f16)tile[c4 + 2][r]; o[3] = (f16)tile[c4 + 3][r];
    *(f16x4*)(out + (size_t)n * Kpad + k0 + c4) = o;
  }
}

// =============================== encoder ===============================
__global__ __launch_bounds__(256) void k_enc1(const f16* __restrict__ xT,
                                              const f16* __restrict__ We1T,
                                              const float* __restrict__ be1,
                                              f16* __restrict__ Henc) {
  __shared__ f16 sA[128 * 40];
  __shared__ f16 sB[128 * 40];
  int m0 = blockIdx.x * 128, n0 = blockIdx.y * 128;
  int b = m0 >> 8, t0 = m0 & 255;
  int tid = threadIdx.x, w = tid >> 6, l = tid & 63;
  int wm = (w >> 1) * 64, wn = (w & 1) * 64;
  int lr = l & 15, lq = l >> 4;
  f32x4 acc[4][4] = {};
  for (int kt = 0; kt < 64; kt++) {
    int k0 = kt * 32;
    __syncthreads();
    int tshift = (k0 < 1024) ? 0 : 1;
    int ks = (k0 < 1024) ? k0 : (k0 - 1024);
    int idx = tid;
#pragma unroll
    for (int rep = 0; rep < 2; rep++, idx += 256) {
      int r = idx >> 2, c = idx & 3;
      *(uint4*)(&sA[r * 40 + c * 8]) =
          *(const uint4*)(xT + ((size_t)(b * 257 + t0 + r + tshift)) * 1024 + ks + c * 8);
      *(uint4*)(&sB[r * 40 + c * 8]) =
          *(const uint4*)(We1T + ((size_t)(n0 + r)) * 2048 + k0 + c * 8);
    }
    __syncthreads();
    f16x8 a[4], bb[4];
#pragma unroll
    for (int i = 0; i < 4; i++) a[i] = *(const f16x8*)(&sA[(wm + i * 16 + lr) * 40 + lq * 8]);
#pragma unroll
    for (int j = 0; j < 4; j++) bb[j] = *(const f16x8*)(&sB[(wn + j * 16 + lr) * 40 + lq * 8]);
#pragma unroll
    for (int i = 0; i < 4; i++)
#pragma unroll
      for (int j = 0; j < 4; j++) acc[i][j] = MFMA16(a[i], bb[j], acc[i][j]);
  }
#pragma unroll
  for (int j = 0; j < 4; j++) {
    int n = n0 + wn + j * 16 + lr;
    float bias = (n < 1056) ? be1[n] : 0.f;
#pragma unroll
    for (int i = 0; i < 4; i++) {
#pragma unroll
      for (int rr = 0; rr < 4; rr++) {
        int m = m0 + wm + i * 16 + lq * 4 + rr;
        float v = acc[i][j][rr] + bias;
        v = v > 0.f ? v : 0.f;
        Henc[(size_t)m * N1P + n] = (f16)v;
      }
    }
  }
}

__global__ __launch_bounds__(256) void k_enc2(const f16* __restrict__ Henc,
                                              const f16* __restrict__ We2T,
                                              const float* __restrict__ be2,
                                              f16* __restrict__ ctrl) {
  __shared__ f16 sA[128 * 40];
  __shared__ f16 sB[64 * 40];
  int m0 = blockIdx.x * 128;
  int tid = threadIdx.x, w = tid >> 6, l = tid & 63;
  int wm = w * 32;
  int lr = l & 15, lq = l >> 4;
  f32x4 acc[2][4] = {};
  for (int kt = 0; kt < 36; kt++) {
    int k0 = kt * 32;
    __syncthreads();
    int idx = tid;
#pragma unroll
    for (int rep = 0; rep < 2; rep++, idx += 256) {
      int r = idx >> 2, c = idx & 3;
      *(uint4*)(&sA[r * 40 + c * 8]) =
          *(const uint4*)(Henc + (size_t)(m0 + r) * N1P + k0 + c * 8);
    }
    {
      int r = tid >> 2, c = tid & 3;
      *(uint4*)(&sB[r * 40 + c * 8]) =
          *(const uint4*)(We2T + (size_t)r * N1P + k0 + c * 8);
    }
    __syncthreads();
    f16x8 a[2], bb[4];
#pragma unroll
    for (int i = 0; i < 2; i++) a[i] = *(const f16x8*)(&sA[(wm + i * 16 + lr) * 40 + lq * 8]);
#pragma unroll
    for (int j = 0; j < 4; j++) bb[j] = *(const f16x8*)(&sB[(j * 16 + lr) * 40 + lq * 8]);
#pragma unroll
    for (int i = 0; i < 2; i++)
#pragma unroll
      for (int j = 0; j < 4; j++) acc[i][j] = MFMA16(a[i], bb[j], acc[i][j]);
  }
#pragma unroll
  for (int j = 0; j < 4; j++) {
    int n = j * 16 + lr;
    float bias = be2[n];
#pragma unroll
    for (int i = 0; i < 2; i++) {
#pragma unroll
      for (int rr = 0; rr < 4; rr++) {
        int m = m0 + wm + i * 16 + lq * 4 + rr;
        int bb_ = m >> 8, t = m & 255;
        ctrl[((size_t)t * 64 + bb_) * 64 + n] = (f16)(acc[i][j][rr] + bias);
      }
    }
  }
}

// =============================== decoder ===============================
// Write-through stores land at the MALL (device coherence point) -> no
// release fence needed. Versioned per-producer u16 flags (no atomic RMWs):
// producer drains data stores (vmcnt0 + syncthreads) then ONE WT flag store.
// tid0 polls all flags with parallel sc0sc1 loads (one RT per iteration).
// Data loads stay plain cached: every exchanged address is t-indexed and
// first-touched after its flag is seen.
__device__ __forceinline__ void st_u64_wt(void* p, uint64_t v) {
  asm volatile("global_store_dwordx2 %0, %1, off sc0 sc1" :: "v"(p), "v"(v) : "memory");
}
__device__ __forceinline__ void st_u16_wt(void* p, unsigned v) {
  asm volatile("global_store_short %0, %1, off sc0 sc1" :: "v"(p), "v"(v) : "memory");
}
__device__ __forceinline__ void ld_fl8(const char* p, uint64_t& a0, uint64_t& a1,
                                       uint64_t& a2, uint64_t& a3, uint64_t& a4,
                                       uint64_t& a5, uint64_t& a6, uint64_t& a7) {
  asm volatile("global_load_dwordx2 %0, %8, off sc0 sc1\n\t"
               "global_load_dwordx2 %1, %8, off offset:8 sc0 sc1\n\t"
               "global_load_dwordx2 %2, %8, off offset:16 sc0 sc1\n\t"
               "global_load_dwordx2 %3, %8, off offset:24 sc0 sc1\n\t"
               "global_load_dwordx2 %4, %8, off offset:32 sc0 sc1\n\t"
               "global_load_dwordx2 %5, %8, off offset:40 sc0 sc1\n\t"
               "global_load_dwordx2 %6, %8, off offset:48 sc0 sc1\n\t"
               "global_load_dwordx2 %7, %8, off offset:56 sc0 sc1\n\t"
               "s_waitcnt vmcnt(0)"
               : "=&v"(a0), "=&v"(a1), "=&v"(a2), "=&v"(a3),
                 "=&v"(a4), "=&v"(a5), "=&v"(a6), "=&v"(a7)
               : "v"(p) : "memory");
}
__device__ __forceinline__ void ld_fl8e(const char* p, uint64_t& a0, uint64_t& a1,
                                        uint64_t& a2, uint64_t& a3, uint64_t& a4,
                                        uint64_t& a5, uint64_t& a6, uint64_t& a7,
                                        unsigned& e) {
  asm volatile("global_load_dwordx2 %0, %9, off sc0 sc1\n\t"
               "global_load_dwordx2 %1, %9, off offset:8 sc0 sc1\n\t"
               "global_load_dwordx2 %2, %9, off offset:16 sc0 sc1\n\t"
               "global_load_dwordx2 %3, %9, off offset:24 sc0 sc1\n\t"
               "global_load_dwordx2 %4, %9, off offset:32 sc0 sc1\n\t"
               "global_load_dwordx2 %5, %9, off offset:40 sc0 sc1\n\t"
               "global_load_dwordx2 %6, %9, off offset:48 sc0 sc1\n\t"
               "global_load_dwordx2 %7, %9, off offset:56 sc0 sc1\n\t"
               "global_load_dword %8, %9, off offset:64 sc0 sc1\n\t"
               "s_waitcnt vmcnt(0)"
               : "=&v"(a0), "=&v"(a1), "=&v"(a2), "=&v"(a3),
                 "=&v"(a4), "=&v"(a5), "=&v"(a6), "=&v"(a7), "=&v"(e)
               : "v"(p) : "memory");
}

// grid = 66 blocks: 2 groups (32 batch rows each) x 33 column-slice blocks.
// Flag region per group (base + g*256): hflags u16[33] at +0, sflags u16[32]
// at +128. MFMA operands are SWAPPED (weights as A-operand): lane then holds
// 4 consecutive output COLUMNS of one row -> one contiguous 8B WT store.
__global__ __launch_bounds__(256, 1) void k_decoder(
    const f16* __restrict__ ctrl, const f16* __restrict__ Wd1T,
    const f16* __restrict__ Wd2T, const float* __restrict__ bd1,
    const float* __restrict__ bd2, f16* __restrict__ states,
    f16* __restrict__ hG, unsigned* __restrict__ flags) {
  extern __shared__ f16 smem[];
  f16* sW1 = smem;
  f16* sW2 = smem + 32 * SW1S;
  int blk = blockIdx.x;
  int g = blk / 33, j = blk % 33;
  int r0 = g * 32, n0 = j * 32;
  int tid = threadIdx.x, w = tid >> 6, l = tid & 63;
  int lr = l & 15, lq = l >> 4;
  int mt = w >> 1, nt = w & 1;

  // pin weight column-slices in LDS (k-contiguous rows from pre-transposed weights)
  for (int idx = tid; idx < 32 * 136; idx += 256) {
    int c = idx / 136, q = idx % 136;
    *(uint4*)(&sW1[c * SW1S + q * 8]) = *(const uint4*)(Wd1T + (size_t)(n0 + c) * 1088 + q * 8);
  }
  if (j < 32) {
    for (int idx = tid; idx < 32 * 132; idx += 256) {
      int c = idx / 132, q = idx % 132;
      *(uint4*)(&sW2[c * SW2S + q * 8]) = *(const uint4*)(Wd2T + (size_t)(n0 + c) * 1056 + q * 8);
    }
  }
  __syncthreads();

  char* fb = (char*)flags + (size_t)g * 256;
  char* hf_me = fb + 2 * j;          // hflags u16[33] @ +0
  char* sf_me = fb + 128 + 2 * j;    // sflags u16[32] @ +128

  int row_b = r0 + mt * 16 + lr;     // this lane's output row (global batch index)
  int wrow = nt * 16 + lr;           // this lane's weight column (local, B-frag load)
  f32x4 b1v = *(const f32x4*)(bd1 + n0 + nt * 16 + lq * 4);
  f32x4 b2v = (j < 32) ? *(const f32x4*)(bd2 + n0 + nt * 16 + lq * 4) : f32x4{};

  for (int t = 0; t < 256; t++) {
    // ---- GEMM1: h_slice = relu(inp @ Wd1_slice + bd1) ----
    // ctrl part has no cross-step dependency: issue before the wait.
    f32x4 acc[4] = {};
    {
      const f16* ctrlRow = ctrl + ((size_t)t * 64 + row_b) * 64;
      f16x8 a0 = *(const f16x8*)(ctrlRow + lq * 8);
      f16x8 b0 = *(const f16x8*)(&sW1[wrow * SW1S + lq * 8]);
      acc[0] = MFMA16(b0, a0, acc[0]);
      f16x8 a1 = *(const f16x8*)(ctrlRow + 32 + lq * 8);
      f16x8 b1 = *(const f16x8*)(&sW1[wrow * SW1S + 32 + lq * 8]);
      acc[1] = MFMA16(b1, a1, acc[1]);
    }
    if (t > 0) {
      if (tid == 0) {
        uint64_t pat = 0x0001000100010001ULL * (uint64_t)t;  // states[t-1] ready
        for (;;) {
          uint64_t a0, a1, a2, a3, a4, a5, a6, a7;
          ld_fl8(fb + 128, a0, a1, a2, a3, a4, a5, a6, a7);
          uint64_t x = ((a0 ^ pat) | (a1 ^ pat)) | ((a2 ^ pat) | (a3 ^ pat)) |
                       ((a4 ^ pat) | (a5 ^ pat)) | ((a6 ^ pat) | (a7 ^ pat));
          if (x == 0) break;
          __builtin_amdgcn_s_sleep(1);
        }
      }
      __syncthreads();
      const f16* sRow = states + ((size_t)(t - 1) * 64 + row_b) * 1024;
      f16x8 av[32];
#pragma unroll
      for (int kt = 0; kt < 32; kt++)
        av[kt] = *(const f16x8*)(sRow + kt * 32 + lq * 8);
#pragma unroll
      for (int kt = 0; kt < 32; kt++) {
        f16x8 bb = *(const f16x8*)(&sW1[wrow * SW1S + (kt + 2) * 32 + lq * 8]);
        acc[(kt + 2) & 3] = MFMA16(bb, av[kt], acc[(kt + 2) & 3]);
      }
    }
    {
      f32x4 r1 = (acc[0] + acc[1]) + (acc[2] + acc[3]);
      f16x4 hv;
#pragma unroll
      for (int rr = 0; rr < 4; rr++) {
        float v = r1[rr] + b1v[rr];
        hv[rr] = (f16)(v > 0.f ? v : 0.f);
      }
      st_u64_wt(hG + ((size_t)t * 64 + row_b) * 1056 + n0 + nt * 16 + lq * 4,
                __builtin_bit_cast(uint64_t, hv));
    }
    asm volatile("s_waitcnt vmcnt(0)" ::: "memory");
    __syncthreads();
    if (tid == 0) st_u16_wt(hf_me, (unsigned)(t + 1));

    // ---- GEMM2: out_slice = h @ Wd2_slice + bd2 ----
    if (j < 32) {
      if (tid == 0) {
        unsigned vv = (unsigned)(t + 1);
        uint64_t pat = 0x0001000100010001ULL * (uint64_t)vv;  // h[t] ready
        for (;;) {
          uint64_t a0, a1, a2, a3, a4, a5, a6, a7; unsigned e;
          ld_fl8e(fb, a0, a1, a2, a3, a4, a5, a6, a7, e);
          uint64_t x = ((a0 ^ pat) | (a1 ^ pat)) | ((a2 ^ pat) | (a3 ^ pat)) |
                       ((a4 ^ pat) | (a5 ^ pat)) | ((a6 ^ pat) | (a7 ^ pat)) |
                       (uint64_t)((e ^ vv) & 0xFFFFu);
          if (x == 0) break;
          __builtin_amdgcn_s_sleep(1);
        }
      }
      __syncthreads();
      f32x4 acc2[4] = {};
      const f16* hRow = hG + ((size_t)t * 64 + row_b) * 1056;
      f16x8 av2[33];
#pragma unroll
      for (int kt = 0; kt < 33; kt++)
        av2[kt] = *(const f16x8*)(hRow + kt * 32 + lq * 8);
#pragma unroll
      for (int kt = 0; kt < 33; kt++) {
        f16x8 bb = *(const f16x8*)(&sW2[wrow * SW2S + kt * 32 + lq * 8]);
        acc2[kt & 3] = MFMA16(bb, av2[kt], acc2[kt & 3]);
      }
      {
        f32x4 r2 = (acc2[0] + acc2[1]) + (acc2[2] + acc2[3]);
        f16x4 ov;
#pragma unroll
        for (int rr = 0; rr < 4; rr++) ov[rr] = (f16)(r2[rr] + b2v[rr]);
        st_u64_wt(states + ((size_t)t * 64 + row_b) * 1024 + n0 + nt * 16 + lq * 4,
                  __builtin_bit_cast(uint64_t, ov));
      }
      asm volatile("s_waitcnt vmcnt(0)" ::: "memory");
      __syncthreads();
      if (tid == 0) st_u16_wt(sf_me, (unsigned)(t + 1));
    }
  }
}

// =============================== output ===============================
__global__ __launch_bounds__(256) void k_out(const f16* __restrict__ states,
                                             float* __restrict__ out) {
  __shared__ float tile[32][33];
  int b = blockIdx.z, t0 = blockIdx.x * 32, s0 = blockIdx.y * 32;
  int r = threadIdx.x >> 3, c4 = (threadIdx.x & 7) * 4;
  f16x4 v = *(const f16x4*)(states + ((size_t)(t0 + r) * 64 + b) * 1024 + s0 + c4);
  tile[r][c4 + 0] = (float)v[0]; tile[r][c4 + 1] = (float)v[1];
  tile[r][c4 + 2] = (float)v[2]; tile[r][c4 + 3] = (float)v[3];
  __syncthreads();
  float4 o;
  o.x = tile[c4 + 0][r]; o.y = tile[c4 + 1][r];
  o.z = tile[c4 + 2][r]; o.w = tile[c4 + 3][r];
  *(float4*)(out + ((size_t)b * 1024 + s0 + r) * 256 + t0 + c4) = o;
}

// =============================== launch ===============================

extern "C" void kernel_launch(void* const* d_in, const int* in_sizes, int n_in,
                              void* d_out, int out_size, void* d_ws, size_t ws_size,
                              hipStream_t stream) {
  const float* x   = (const float*)d_in[0];
  const float* We1 = (const float*)d_in[1];
  const float* be1 = (const float*)d_in[2];
  const float* We2 = (const float*)d_in[3];
  const float* be2 = (const float*)d_in[4];
  const float* Wd1 = (const float*)d_in[5];
  const float* bd1 = (const float*)d_in[6];
  const float* Wd2 = (const float*)d_in[7];
  const float* bd2 = (const float*)d_in[8];
  float* outp = (float*)d_out;

  if (ws_size < WS_NEED) return;
  char* ws = (char*)d_ws;
  unsigned* flags = (unsigned*)(ws + OFF_FLAGS);
  f16* xT    = (f16*)(ws + OFF_XT);
  f16* We1T  = (f16*)(ws + OFF_WE1T);
  f16* We2T  = (f16*)(ws + OFF_WE2T);
  f16* Wd1T  = (f16*)(ws + OFF_WD1T);
  f16* Wd2T  = (f16*)(ws + OFF_WD2T);
  f16* Henc  = (f16*)(ws + OFF_HENC);
  f16* ctrl  = (f16*)(ws + OFF_CTRL);
  f16* st    = (f16*)(ws + OFF_ST);
  f16* hG    = Henc;  // decoder h exchange, t-indexed [256][64][1056], aliases Henc (dead after enc2)

  (void)hipMemsetAsync(flags, 0, 4096, stream);
  k_zero_x0<<<64, 256, 0, stream>>>(xT);
  k_transpose_x<<<dim3(32, 8, 64), 256, 0, stream>>>(x, xT);
  k_transpose_w<<<dim3(64, 36), 256, 0, stream>>>(We1, We1T, 2048, 1056, 2048, 1152);
  k_transpose_w<<<dim3(36, 2), 256, 0, stream>>>(We2, We2T, 1056, 64, 1152, 64);
  k_transpose_w<<<dim3(34, 33), 256, 0, stream>>>(Wd1, Wd1T, 1088, 1056, 1088, 1056);
  k_transpose_w<<<dim3(33, 32), 256, 0, stream>>>(Wd2, Wd2T, 1056, 1024, 1056, 1024);
  k_enc1<<<dim3(128, 9), 256, 0, stream>>>(xT, We1T, be1, Henc);
  k_enc2<<<128, 256, 0, stream>>>(Henc, We2T, be2, ctrl);
  (void)hipFuncSetAttribute((const void*)k_decoder, hipFuncAttributeMaxDynamicSharedMemorySize,
                            (int)DEC_LDS);
  k_decoder<<<66, 256, DEC_LDS, stream>>>(ctrl, Wd1T, Wd2T, bd1, bd2, st, hG, flags);
  k_out<<<dim3(8, 32, 64), 256, 0, stream>>>(st, outp);
}

// Round 5
// 2688.769 us; speedup vs baseline: 1.1752x; 1.1344x over previous
//
#include <hip/hip_runtime.h>
#include <hip/hip_fp16.h>
#include <stdint.h>

typedef _Float16 f16;
typedef _Float16 f16x8 __attribute__((ext_vector_type(8)));
typedef _Float16 f16x4 __attribute__((ext_vector_type(4)));
typedef float    f32x4 __attribute__((ext_vector_type(4)));

#define MFMA16(a, b, c) __builtin_amdgcn_mfma_f32_16x16x32_f16((a), (b), (c), 0, 0, 0)

// ---- problem dims ----
static constexpr int N1P = 1152;   // enc layer-1 N (1056) padded to 9*128

// ---- workspace layout (bytes, all 256-aligned) ----
static constexpr size_t OFF_FLAGS = 0;                                    // legacy 4 KiB (unused now)
static constexpr size_t OFF_XT    = 4096;                                 // f16 [64][257][1024] (row 0 = zeros = prev at t=0)
static constexpr size_t OFF_WE1T  = OFF_XT   + (size_t)64 * 257 * 1024 * 2;  // f16 [1152][2048]
static constexpr size_t OFF_WE2T  = OFF_WE1T + (size_t)1152 * 2048 * 2;      // f16 [64][1152]
static constexpr size_t OFF_WD1T  = OFF_WE2T + (size_t)64 * 1152 * 2;        // f16 [1056][1088]
static constexpr size_t OFF_WD2T  = OFF_WD1T + (size_t)1056 * 1088 * 2;      // f16 [1024][1056]
static constexpr size_t OFF_HENC  = OFF_WD2T + (size_t)1024 * 1056 * 2;      // f16 [16384][1152]; decoder reuses as hG[256][64][1056]
static constexpr size_t OFF_CTRL  = OFF_HENC + (size_t)16384 * 1152 * 2;     // f16 [256][64][64]
static constexpr size_t OFF_ST    = OFF_CTRL + (size_t)256 * 64 * 64 * 2;    // f16 [256][64][1024] (decoder outputs)
static constexpr size_t OFF_HG    = OFF_ST   + (size_t)256 * 64 * 1024 * 2;  // 135 KiB spare: per-LINE flag region
static constexpr size_t WS_NEED   = OFF_HG   + (size_t)64 * 1056 * 2;

// per-line flags: per group base = OFF_HG + g*8192
//   hflag[j] (j=0..32) at byte j*64       (each on its OWN 64B line)
//   sflag[j] (j=0..31) at byte 4096+j*64
static constexpr size_t FLAG_BYTES = 16384;

// decoder LDS: Wd1 slice [32][1096] + Wd2 slice [32][1064] (padded strides)
static constexpr int SW1S = 1096, SW2S = 1064;
static constexpr size_t DEC_LDS = (size_t)32 * (SW1S + SW2S) * 2;  // 138240

// =============================== prep kernels ===============================

__global__ __launch_bounds__(256) void k_zero_x0(f16* __restrict__ xT) {
  f16x4 z = {};
  *(f16x4*)(xT + (size_t)blockIdx.x * 257 * 1024 + threadIdx.x * 4) = z;
}

// x [64][1024][256] f32  ->  xT[b][t+1][s] f16   (xT row 0 stays zero)
__global__ __launch_bounds__(256) void k_transpose_x(const float* __restrict__ x,
                                                     f16* __restrict__ xT) {
  __shared__ float tile[32][33];
  int b = blockIdx.z, s0 = blockIdx.x * 32, t0 = blockIdx.y * 32;
  int r = threadIdx.x >> 3, c4 = (threadIdx.x & 7) * 4;
  const float4 v = *(const float4*)(x + ((size_t)b * 1024 + s0 + r) * 256 + t0 + c4);
  tile[r][c4 + 0] = v.x; tile[r][c4 + 1] = v.y;
  tile[r][c4 + 2] = v.z; tile[r][c4 + 3] = v.w;
  __syncthreads();
  f16x4 o;
  o[0] = (f16)tile[c4 + 0][r]; o[1] = (f16)tile[c4 + 1][r];
  o[2] = (f16)tile[c4 + 2][r]; o[3] = (f16)tile[c4 + 3][r];
  *(f16x4*)(xT + ((size_t)b * 257 + t0 + r + 1) * 1024 + s0 + c4) = o;
}

// in [K][N] f32 -> out [Npad][Kpad] f16 (zero pad where k>=K or n>=N)
__global__ __launch_bounds__(256) void k_transpose_w(const float* __restrict__ in,
                                                     f16* __restrict__ out,
                                                     int K, int N, int Kpad, int Npad) {
  __shared__ float tile[32][33];
  int k0 = blockIdx.x * 32, n0 = blockIdx.y * 32;
  int r = threadIdx.x >> 3, c4 = (threadIdx.x & 7) * 4;
#pragma unroll
  for (int i = 0; i < 4; i++) {
    int k = k0 + r, n = n0 + c4 + i;
    tile[r][c4 + i] = (k < K && n < N) ? in[(size_t)k * N + n] : 0.f;
  }
  __syncthreads();
  int n = n0 + r;
  if (n < Npad) {
    f16x4 o;
    o[0] = (f16)tile[c4 + 0][r]; o[1] = (f16)tile[c4 + 1][r];
    o[2] = (f16)tile[c4 + 2][r]; o[3] = (f16)tile[c4 + 3][r];
    *(f16x4*)(out + (size_t)n * Kpad + k0 + c4) = o;
  }
}

// =============================== encoder ===============================
__global__ __launch_bounds__(256) void k_enc1(const f16* __restrict__ xT,
                                              const f16* __restrict__ We1T,
                                              const float* __restrict__ be1,
                                              f16* __restrict__ Henc) {
  __shared__ f16 sA[128 * 40];
  __shared__ f16 sB[128 * 40];
  int m0 = blockIdx.x * 128, n0 = blockIdx.y * 128;
  int b = m0 >> 8, t0 = m0 & 255;
  int tid = threadIdx.x, w = tid >> 6, l = tid & 63;
  int wm = (w >> 1) * 64, wn = (w & 1) * 64;
  int lr = l & 15, lq = l >> 4;
  f32x4 acc[4][4] = {};
  for (int kt = 0; kt < 64; kt++) {
    int k0 = kt * 32;
    __syncthreads();
    int tshift = (k0 < 1024) ? 0 : 1;
    int ks = (k0 < 1024) ? k0 : (k0 - 1024);
    int idx = tid;
#pragma unroll
    for (int rep = 0; rep < 2; rep++, idx += 256) {
      int r = idx >> 2, c = idx & 3;
      *(uint4*)(&sA[r * 40 + c * 8]) =
          *(const uint4*)(xT + ((size_t)(b * 257 + t0 + r + tshift)) * 1024 + ks + c * 8);
      *(uint4*)(&sB[r * 40 + c * 8]) =
          *(const uint4*)(We1T + ((size_t)(n0 + r)) * 2048 + k0 + c * 8);
    }
    __syncthreads();
    f16x8 a[4], bb[4];
#pragma unroll
    for (int i = 0; i < 4; i++) a[i] = *(const f16x8*)(&sA[(wm + i * 16 + lr) * 40 + lq * 8]);
#pragma unroll
    for (int j = 0; j < 4; j++) bb[j] = *(const f16x8*)(&sB[(wn + j * 16 + lr) * 40 + lq * 8]);
#pragma unroll
    for (int i = 0; i < 4; i++)
#pragma unroll
      for (int j = 0; j < 4; j++) acc[i][j] = MFMA16(a[i], bb[j], acc[i][j]);
  }
#pragma unroll
  for (int j = 0; j < 4; j++) {
    int n = n0 + wn + j * 16 + lr;
    float bias = (n < 1056) ? be1[n] : 0.f;
#pragma unroll
    for (int i = 0; i < 4; i++) {
#pragma unroll
      for (int rr = 0; rr < 4; rr++) {
        int m = m0 + wm + i * 16 + lq * 4 + rr;
        float v = acc[i][j][rr] + bias;
        v = v > 0.f ? v : 0.f;
        Henc[(size_t)m * N1P + n] = (f16)v;
      }
    }
  }
}

__global__ __launch_bounds__(256) void k_enc2(const f16* __restrict__ Henc,
                                              const f16* __restrict__ We2T,
                                              const float* __restrict__ be2,
                                              f16* __restrict__ ctrl) {
  __shared__ f16 sA[128 * 40];
  __shared__ f16 sB[64 * 40];
  int m0 = blockIdx.x * 128;
  int tid = threadIdx.x, w = tid >> 6, l = tid & 63;
  int wm = w * 32;
  int lr = l & 15, lq = l >> 4;
  f32x4 acc[2][4] = {};
  for (int kt = 0; kt < 36; kt++) {
    int k0 = kt * 32;
    __syncthreads();
    int idx = tid;
#pragma unroll
    for (int rep = 0; rep < 2; rep++, idx += 256) {
      int r = idx >> 2, c = idx & 3;
      *(uint4*)(&sA[r * 40 + c * 8]) =
          *(const uint4*)(Henc + (size_t)(m0 + r) * N1P + k0 + c * 8);
    }
    {
      int r = tid >> 2, c = tid & 3;
      *(uint4*)(&sB[r * 40 + c * 8]) =
          *(const uint4*)(We2T + (size_t)r * N1P + k0 + c * 8);
    }
    __syncthreads();
    f16x8 a[2], bb[4];
#pragma unroll
    for (int i = 0; i < 2; i++) a[i] = *(const f16x8*)(&sA[(wm + i * 16 + lr) * 40 + lq * 8]);
#pragma unroll
    for (int j = 0; j < 4; j++) bb[j] = *(const f16x8*)(&sB[(j * 16 + lr) * 40 + lq * 8]);
#pragma unroll
    for (int i = 0; i < 2; i++)
#pragma unroll
      for (int j = 0; j < 4; j++) acc[i][j] = MFMA16(a[i], bb[j], acc[i][j]);
  }
#pragma unroll
  for (int j = 0; j < 4; j++) {
    int n = j * 16 + lr;
    float bias = be2[n];
#pragma unroll
    for (int i = 0; i < 2; i++) {
#pragma unroll
      for (int rr = 0; rr < 4; rr++) {
        int m = m0 + wm + i * 16 + lq * 4 + rr;
        int bb_ = m >> 8, t = m & 255;
        ctrl[((size_t)t * 64 + bb_) * 64 + n] = (f16)(acc[i][j][rr] + bias);
      }
    }
  }
}

// =============================== decoder ===============================
// Write-through stores land at the MALL (device coherence point) -> no
// release fence needed. PER-LINE versioned flags: each producer owns its own
// 64B flag line (no same-line writers -> no MALL merge serialization; poll
// reads never queue behind another producer's partial-write merges).
// Consumer wave 0 polls all flag lines in parallel (one lane per line, one
// MALL round trip per iteration) and releases the block via __syncthreads.
// Data loads stay plain cached: every exchanged address is t-indexed and
// first-touched after its flag is seen (L2s are invalidated at dispatch
// boundaries, so no stale lines within this dispatch).
__device__ __forceinline__ void st_u64_wt(void* p, uint64_t v) {
  asm volatile("global_store_dwordx2 %0, %1, off sc0 sc1" :: "v"(p), "v"(v) : "memory");
}
__device__ __forceinline__ void st_u16_wt(void* p, unsigned v) {
  asm volatile("global_store_short %0, %1, off sc0 sc1" :: "v"(p), "v"(v) : "memory");
}
__device__ __forceinline__ unsigned ld_u16_wt(const void* p) {
  unsigned r;
  asm volatile("global_load_ushort %0, %1, off sc0 sc1\n\ts_waitcnt vmcnt(0)"
               : "=v"(r) : "v"(p) : "memory");
  return r;
}

// grid = 66 blocks: 2 groups (32 batch rows each) x 33 column-slice blocks.
// MFMA operands are SWAPPED (weights as A-operand): each lane holds 4
// consecutive output columns of one row -> one contiguous 8B WT store.
__global__ __launch_bounds__(256, 1) void k_decoder(
    const f16* __restrict__ ctrl, const f16* __restrict__ Wd1T,
    const f16* __restrict__ Wd2T, const float* __restrict__ bd1,
    const float* __restrict__ bd2, f16* __restrict__ states,
    f16* __restrict__ hG, unsigned* __restrict__ flags) {
  extern __shared__ f16 smem[];
  f16* sW1 = smem;
  f16* sW2 = smem + 32 * SW1S;
  int blk = blockIdx.x;
  int g = blk / 33, j = blk % 33;
  int r0 = g * 32, n0 = j * 32;
  int tid = threadIdx.x, w = tid >> 6, l = tid & 63;
  int lr = l & 15, lq = l >> 4;
  int mt = w >> 1, nt = w & 1;

  // pin weight column-slices in LDS (k-contiguous rows from pre-transposed weights)
  for (int idx = tid; idx < 32 * 136; idx += 256) {
    int c = idx / 136, q = idx % 136;
    *(uint4*)(&sW1[c * SW1S + q * 8]) = *(const uint4*)(Wd1T + (size_t)(n0 + c) * 1088 + q * 8);
  }
  if (j < 32) {
    for (int idx = tid; idx < 32 * 132; idx += 256) {
      int c = idx / 132, q = idx % 132;
      *(uint4*)(&sW2[c * SW2S + q * 8]) = *(const uint4*)(Wd2T + (size_t)(n0 + c) * 1056 + q * 8);
    }
  }
  __syncthreads();

  char* fb = (char*)flags + (size_t)g * 8192;
  char* hf_me = fb + (size_t)j * 64;           // my hflag line
  char* sf_me = fb + 4096 + (size_t)j * 64;    // my sflag line (j<32)
  // poll addresses for wave-parallel flag check (one lane per 64B line)
  const char* hf_poll = fb + (size_t)l * 64;          // lanes 0..32
  const char* sf_poll = fb + 4096 + (size_t)l * 64;   // lanes 0..31

  int row_b = r0 + mt * 16 + lr;     // this lane's output row (global batch index)
  int wrow = nt * 16 + lr;           // this lane's weight column (local, B-frag load)
  f32x4 b1v = *(const f32x4*)(bd1 + n0 + nt * 16 + lq * 4);
  f32x4 b2v = (j < 32) ? *(const f32x4*)(bd2 + n0 + nt * 16 + lq * 4) : f32x4{};

  for (int t = 0; t < 256; t++) {
    // ---- GEMM1: h_slice = relu(inp @ Wd1_slice + bd1) ----
    // ctrl part has no cross-step dependency: issue before the wait.
    f32x4 acc[4] = {};
    {
      const f16* ctrlRow = ctrl + ((size_t)t * 64 + row_b) * 64;
      f16x8 a0 = *(const f16x8*)(ctrlRow + lq * 8);
      f16x8 b0 = *(const f16x8*)(&sW1[wrow * SW1S + lq * 8]);
      acc[0] = MFMA16(b0, a0, acc[0]);
      f16x8 a1 = *(const f16x8*)(ctrlRow + 32 + lq * 8);
      f16x8 b1 = *(const f16x8*)(&sW1[wrow * SW1S + 32 + lq * 8]);
      acc[1] = MFMA16(b1, a1, acc[1]);
    }
    if (t > 0) {
      // wait for all 32 sflags == t (states[t-1] ready); wave 0 polls,
      // one lane per flag line, one MALL RT per iteration
      if (w == 0) {
        unsigned need = (unsigned)t;
        for (;;) {
          unsigned v = need;
          if (l < 32) v = ld_u16_wt(sf_poll);
          if (__all((int)(v == need))) break;
        }
      }
      __syncthreads();
      const f16* sRow = states + ((size_t)(t - 1) * 64 + row_b) * 1024;
      f16x8 av[32];
#pragma unroll
      for (int kt = 0; kt < 32; kt++)
        av[kt] = *(const f16x8*)(sRow + kt * 32 + lq * 8);
#pragma unroll
      for (int kt = 0; kt < 32; kt++) {
        f16x8 bb = *(const f16x8*)(&sW1[wrow * SW1S + (kt + 2) * 32 + lq * 8]);
        acc[(kt + 2) & 3] = MFMA16(bb, av[kt], acc[(kt + 2) & 3]);
      }
    }
    {
      f32x4 r1 = (acc[0] + acc[1]) + (acc[2] + acc[3]);
      f16x4 hv;
#pragma unroll
      for (int rr = 0; rr < 4; rr++) {
        float v = r1[rr] + b1v[rr];
        hv[rr] = (f16)(v > 0.f ? v : 0.f);
      }
      st_u64_wt(hG + ((size_t)t * 64 + row_b) * 1056 + n0 + nt * 16 + lq * 4,
                __builtin_bit_cast(uint64_t, hv));
    }
    asm volatile("s_waitcnt vmcnt(0)" ::: "memory");
    __syncthreads();
    if (tid == 0) st_u16_wt(hf_me, (unsigned)(t + 1));

    // ---- GEMM2: out_slice = h @ Wd2_slice + bd2 ----
    if (j < 32) {
      // wait for all 33 hflags == t+1 (h[t] ready)
      if (w == 0) {
        unsigned need = (unsigned)(t + 1);
        for (;;) {
          unsigned v = need;
          if (l < 33) v = ld_u16_wt(hf_poll);
          if (__all((int)(v == need))) break;
        }
      }
      __syncthreads();
      f32x4 acc2[4] = {};
      const f16* hRow = hG + ((size_t)t * 64 + row_b) * 1056;
      f16x8 av2[33];
#pragma unroll
      for (int kt = 0; kt < 33; kt++)
        av2[kt] = *(const f16x8*)(hRow + kt * 32 + lq * 8);
#pragma unroll
      for (int kt = 0; kt < 33; kt++) {
        f16x8 bb = *(const f16x8*)(&sW2[wrow * SW2S + kt * 32 + lq * 8]);
        acc2[kt & 3] = MFMA16(bb, av2[kt], acc2[kt & 3]);
      }
      {
        f32x4 r2 = (acc2[0] + acc2[1]) + (acc2[2] + acc2[3]);
        f16x4 ov;
#pragma unroll
        for (int rr = 0; rr < 4; rr++) ov[rr] = (f16)(r2[rr] + b2v[rr]);
        st_u64_wt(states + ((size_t)t * 64 + row_b) * 1024 + n0 + nt * 16 + lq * 4,
                  __builtin_bit_cast(uint64_t, ov));
      }
      asm volatile("s_waitcnt vmcnt(0)" ::: "memory");
      __syncthreads();
      if (tid == 0) st_u16_wt(sf_me, (unsigned)(t + 1));
    }
  }
}

// =============================== output ===============================
__global__ __launch_bounds__(256) void k_out(const f16* __restrict__ states,
                                             float* __restrict__ out) {
  __shared__ float tile[32][33];
  int b = blockIdx.z, t0 = blockIdx.x * 32, s0 = blockIdx.y * 32;
  int r = threadIdx.x >> 3, c4 = (threadIdx.x & 7) * 4;
  f16x4 v = *(const f16x4*)(states + ((size_t)(t0 + r) * 64 + b) * 1024 + s0 + c4);
  tile[r][c4 + 0] = (float)v[0]; tile[r][c4 + 1] = (float)v[1];
  tile[r][c4 + 2] = (float)v[2]; tile[r][c4 + 3] = (float)v[3];
  __syncthreads();
  float4 o;
  o.x = tile[c4 + 0][r]; o.y = tile[c4 + 1][r];
  o.z = tile[c4 + 2][r]; o.w = tile[c4 + 3][r];
  *(float4*)(out + ((size_t)b * 1024 + s0 + r) * 256 + t0 + c4) = o;
}

// =============================== launch ===============================

extern "C" void kernel_launch(void* const* d_in, const int* in_sizes, int n_in,
                              void* d_out, int out_size, void* d_ws, size_t ws_size,
                              hipStream_t stream) {
  const float* x   = (const float*)d_in[0];
  const float* We1 = (const float*)d_in[1];
  const float* be1 = (const float*)d_in[2];
  const float* We2 = (const float*)d_in[3];
  const float* be2 = (const float*)d_in[4];
  const float* Wd1 = (const float*)d_in[5];
  const float* bd1 = (const float*)d_in[6];
  const float* Wd2 = (const float*)d_in[7];
  const float* bd2 = (const float*)d_in[8];
  float* outp = (float*)d_out;

  if (ws_size < WS_NEED) return;
  char* ws = (char*)d_ws;
  f16* xT    = (f16*)(ws + OFF_XT);
  f16* We1T  = (f16*)(ws + OFF_WE1T);
  f16* We2T  = (f16*)(ws + OFF_WE2T);
  f16* Wd1T  = (f16*)(ws + OFF_WD1T);
  f16* Wd2T  = (f16*)(ws + OFF_WD2T);
  f16* Henc  = (f16*)(ws + OFF_HENC);
  f16* ctrl  = (f16*)(ws + OFF_CTRL);
  f16* st    = (f16*)(ws + OFF_ST);
  f16* hG    = Henc;  // decoder h exchange, t-indexed [256][64][1056], aliases Henc (dead after enc2)
  unsigned* flags = (unsigned*)(ws + OFF_HG);  // per-line flag region (legacy spare)

  (void)hipMemsetAsync(flags, 0, FLAG_BYTES, stream);
  k_zero_x0<<<64, 256, 0, stream>>>(xT);
  k_transpose_x<<<dim3(32, 8, 64), 256, 0, stream>>>(x, xT);
  k_transpose_w<<<dim3(64, 36), 256, 0, stream>>>(We1, We1T, 2048, 1056, 2048, 1152);
  k_transpose_w<<<dim3(36, 2), 256, 0, stream>>>(We2, We2T, 1056, 64, 1152, 64);
  k_transpose_w<<<dim3(34, 33), 256, 0, stream>>>(Wd1, Wd1T, 1088, 1056, 1088, 1056);
  k_transpose_w<<<dim3(33, 32), 256, 0, stream>>>(Wd2, Wd2T, 1056, 1024, 1056, 1024);
  k_enc1<<<dim3(128, 9), 256, 0, stream>>>(xT, We1T, be1, Henc);
  k_enc2<<<128, 256, 0, stream>>>(Henc, We2T, be2, ctrl);
  (void)hipFuncSetAttribute((const void*)k_decoder, hipFuncAttributeMaxDynamicSharedMemorySize,
                            (int)DEC_LDS);
  k_decoder<<<66, 256, DEC_LDS, stream>>>(ctrl, Wd1T, Wd2T, bd1, bd2, st, hG, flags);
  k_out<<<dim3(8, 32, 64), 256, 0, stream>>>(st, outp);
}

// Round 6
// 1589.064 us; speedup vs baseline: 1.9886x; 1.6920x over previous
//
#include <hip/hip_runtime.h>
#include <hip/hip_fp16.h>
#include <stdint.h>

typedef _Float16 f16;
typedef _Float16 f16x8 __attribute__((ext_vector_type(8)));
typedef _Float16 f16x4 __attribute__((ext_vector_type(4)));
typedef float    f32x4 __attribute__((ext_vector_type(4)));

#define MFMA16(a, b, c) __builtin_amdgcn_mfma_f32_16x16x32_f16((a), (b), (c), 0, 0, 0)

// ---- problem dims ----
static constexpr int N1P = 1152;   // enc layer-1 N (1056) padded to 9*128

// ---- workspace layout (bytes, all 256-aligned) ----
static constexpr size_t OFF_FLAGS = 0;                                    // legacy (unused)
static constexpr size_t OFF_XT    = 4096;                                 // f16 [64][257][1024]; later Whi/Wlo
static constexpr size_t OFF_WE1T  = OFF_XT   + (size_t)64 * 257 * 1024 * 2;  // f16 [1152][2048]; later Wd2C
static constexpr size_t OFF_WE2T  = OFF_WE1T + (size_t)1152 * 2048 * 2;      // f16 [64][1152]
static constexpr size_t OFF_WD1T  = OFF_WE2T + (size_t)64 * 1152 * 2;        // f16 [1056][1088]
static constexpr size_t OFF_WD2T  = OFF_WD1T + (size_t)1056 * 1088 * 2;      // f16 [1024][1056]
static constexpr size_t OFF_HENC  = OFF_WD2T + (size_t)1024 * 1056 * 2;      // f16 [16384][1152]; decoder reuses as hG[256][64][1056]
static constexpr size_t OFF_CTRL  = OFF_HENC + (size_t)16384 * 1152 * 2;     // f16 [256][64][64]
static constexpr size_t OFF_ST    = OFF_CTRL + (size_t)256 * 64 * 64 * 2;    // f16 [256][64][1024] (decoder outputs)
static constexpr size_t OFF_HG    = OFF_ST   + (size_t)256 * 64 * 1024 * 2;  // 135 KiB spare: flags + bprime
static constexpr size_t WS_NEED   = OFF_HG   + (size_t)64 * 1056 * 2;

// flag region: per group base = OFF_HG + g*8192, hflag[j] (j=0..32) at byte j*64
static constexpr size_t FLAG_BYTES = 16384;
static constexpr size_t OFF_BPRIME = OFF_HG + FLAG_BYTES;   // f32 [1056]

// composed-weight buffers (alias XT / WE1T regions, dead after enc1)
static constexpr size_t WHI_BYTES = (size_t)1056 * 1120 * 2;  // 2,365,440 (256-aligned)

// decoder LDS: M_lo slice [32][1128] (stride 1128 = 8*141, odd 16B multiple)
static constexpr int SWS = 1128;
static constexpr size_t DEC_LDS = (size_t)32 * SWS * 2;  // 72192

// =============================== prep kernels ===============================

__global__ __launch_bounds__(256) void k_zero_x0(f16* __restrict__ xT) {
  f16x4 z = {};
  *(f16x4*)(xT + (size_t)blockIdx.x * 257 * 1024 + threadIdx.x * 4) = z;
}

// x [64][1024][256] f32  ->  xT[b][t+1][s] f16   (xT row 0 stays zero)
__global__ __launch_bounds__(256) void k_transpose_x(const float* __restrict__ x,
                                                     f16* __restrict__ xT) {
  __shared__ float tile[32][33];
  int b = blockIdx.z, s0 = blockIdx.x * 32, t0 = blockIdx.y * 32;
  int r = threadIdx.x >> 3, c4 = (threadIdx.x & 7) * 4;
  const float4 v = *(const float4*)(x + ((size_t)b * 1024 + s0 + r) * 256 + t0 + c4);
  tile[r][c4 + 0] = v.x; tile[r][c4 + 1] = v.y;
  tile[r][c4 + 2] = v.z; tile[r][c4 + 3] = v.w;
  __syncthreads();
  f16x4 o;
  o[0] = (f16)tile[c4 + 0][r]; o[1] = (f16)tile[c4 + 1][r];
  o[2] = (f16)tile[c4 + 2][r]; o[3] = (f16)tile[c4 + 3][r];
  *(f16x4*)(xT + ((size_t)b * 257 + t0 + r + 1) * 1024 + s0 + c4) = o;
}

// in [K][N] f32 -> out [Npad][Kpad] f16 (zero pad where k>=K or n>=N)
__global__ __launch_bounds__(256) void k_transpose_w(const float* __restrict__ in,
                                                     f16* __restrict__ out,
                                                     int K, int N, int Kpad, int Npad) {
  __shared__ float tile[32][33];
  int k0 = blockIdx.x * 32, n0 = blockIdx.y * 32;
  int r = threadIdx.x >> 3, c4 = (threadIdx.x & 7) * 4;
#pragma unroll
  for (int i = 0; i < 4; i++) {
    int k = k0 + r, n = n0 + c4 + i;
    tile[r][c4 + i] = (k < K && n < N) ? in[(size_t)k * N + n] : 0.f;
  }
  __syncthreads();
  int n = n0 + r;
  if (n < Npad) {
    f16x4 o;
    o[0] = (f16)tile[c4 + 0][r]; o[1] = (f16)tile[c4 + 1][r];
    o[2] = (f16)tile[c4 + 2][r]; o[3] = (f16)tile[c4 + 3][r];
    *(f16x4*)(out + (size_t)n * Kpad + k0 + c4) = o;
  }
}

// Wd2 f32 [1056][1024] -> f16 row-major copy (s-contiguous, for k_mkM B operand)
__global__ __launch_bounds__(256) void k_cast(const float* __restrict__ in,
                                              f16* __restrict__ out) {
  int i = (blockIdx.x * 256 + threadIdx.x) * 8;
  if (i >= 1056 * 1024) return;
  float4 v0 = *(const float4*)(in + i);
  float4 v1 = *(const float4*)(in + i + 4);
  f16x8 o;
  o[0] = (f16)v0.x; o[1] = (f16)v0.y; o[2] = (f16)v0.z; o[3] = (f16)v0.w;
  o[4] = (f16)v1.x; o[5] = (f16)v1.y; o[6] = (f16)v1.z; o[7] = (f16)v1.w;
  *(f16x8*)(out + i) = o;
}

// =============================== encoder ===============================
__global__ __launch_bounds__(256) void k_enc1(const f16* __restrict__ xT,
                                              const f16* __restrict__ We1T,
                                              const float* __restrict__ be1,
                                              f16* __restrict__ Henc) {
  __shared__ f16 sA[128 * 40];
  __shared__ f16 sB[128 * 40];
  int m0 = blockIdx.x * 128, n0 = blockIdx.y * 128;
  int b = m0 >> 8, t0 = m0 & 255;
  int tid = threadIdx.x, w = tid >> 6, l = tid & 63;
  int wm = (w >> 1) * 64, wn = (w & 1) * 64;
  int lr = l & 15, lq = l >> 4;
  f32x4 acc[4][4] = {};
  for (int kt = 0; kt < 64; kt++) {
    int k0 = kt * 32;
    __syncthreads();
    int tshift = (k0 < 1024) ? 0 : 1;
    int ks = (k0 < 1024) ? k0 : (k0 - 1024);
    int idx = tid;
#pragma unroll
    for (int rep = 0; rep < 2; rep++, idx += 256) {
      int r = idx >> 2, c = idx & 3;
      *(uint4*)(&sA[r * 40 + c * 8]) =
          *(const uint4*)(xT + ((size_t)(b * 257 + t0 + r + tshift)) * 1024 + ks + c * 8);
      *(uint4*)(&sB[r * 40 + c * 8]) =
          *(const uint4*)(We1T + ((size_t)(n0 + r)) * 2048 + k0 + c * 8);
    }
    __syncthreads();
    f16x8 a[4], bb[4];
#pragma unroll
    for (int i = 0; i < 4; i++) a[i] = *(const f16x8*)(&sA[(wm + i * 16 + lr) * 40 + lq * 8]);
#pragma unroll
    for (int j = 0; j < 4; j++) bb[j] = *(const f16x8*)(&sB[(wn + j * 16 + lr) * 40 + lq * 8]);
#pragma unroll
    for (int i = 0; i < 4; i++)
#pragma unroll
      for (int j = 0; j < 4; j++) acc[i][j] = MFMA16(a[i], bb[j], acc[i][j]);
  }
#pragma unroll
  for (int j = 0; j < 4; j++) {
    int n = n0 + wn + j * 16 + lr;
    float bias = (n < 1056) ? be1[n] : 0.f;
#pragma unroll
    for (int i = 0; i < 4; i++) {
#pragma unroll
      for (int rr = 0; rr < 4; rr++) {
        int m = m0 + wm + i * 16 + lq * 4 + rr;
        float v = acc[i][j][rr] + bias;
        v = v > 0.f ? v : 0.f;
        Henc[(size_t)m * N1P + n] = (f16)v;
      }
    }
  }
}

__global__ __launch_bounds__(256) void k_enc2(const f16* __restrict__ Henc,
                                              const f16* __restrict__ We2T,
                                              const float* __restrict__ be2,
                                              f16* __restrict__ ctrl) {
  __shared__ f16 sA[128 * 40];
  __shared__ f16 sB[64 * 40];
  int m0 = blockIdx.x * 128;
  int tid = threadIdx.x, w = tid >> 6, l = tid & 63;
  int wm = w * 32;
  int lr = l & 15, lq = l >> 4;
  f32x4 acc[2][4] = {};
  for (int kt = 0; kt < 36; kt++) {
    int k0 = kt * 32;
    __syncthreads();
    int idx = tid;
#pragma unroll
    for (int rep = 0; rep < 2; rep++, idx += 256) {
      int r = idx >> 2, c = idx & 3;
      *(uint4*)(&sA[r * 40 + c * 8]) =
          *(const uint4*)(Henc + (size_t)(m0 + r) * N1P + k0 + c * 8);
    }
    {
      int r = tid >> 2, c = tid & 3;
      *(uint4*)(&sB[r * 40 + c * 8]) =
          *(const uint4*)(We2T + (size_t)r * N1P + k0 + c * 8);
    }
    __syncthreads();
    f16x8 a[2], bb[4];
#pragma unroll
    for (int i = 0; i < 2; i++) a[i] = *(const f16x8*)(&sA[(wm + i * 16 + lr) * 40 + lq * 8]);
#pragma unroll
    for (int j = 0; j < 4; j++) bb[j] = *(const f16x8*)(&sB[(j * 16 + lr) * 40 + lq * 8]);
#pragma unroll
    for (int i = 0; i < 2; i++)
#pragma unroll
      for (int j = 0; j < 4; j++) acc[i][j] = MFMA16(a[i], bb[j], acc[i][j]);
  }
#pragma unroll
  for (int j = 0; j < 4; j++) {
    int n = j * 16 + lr;
    float bias = be2[n];
#pragma unroll
    for (int i = 0; i < 2; i++) {
#pragma unroll
      for (int rr = 0; rr < 4; rr++) {
        int m = m0 + wm + i * 16 + lq * 4 + rr;
        int bb_ = m >> 8, t = m & 255;
        ctrl[((size_t)t * 64 + bb_) * 64 + n] = (f16)(acc[i][j][rr] + bias);
      }
    }
  }
}

// =============================== composed recurrence weights ===============================
// M[h,j] = sum_s Wd2[h,s] * Wd1[64+s, j];  C[j][h] = sum_k Wd1T[j][64+k]*Wd2C[h][k]
// stored as Whi/Wlo[j][64+h] (hi/lo f16 split of the f32 product).
__global__ __launch_bounds__(256) void k_mkM(const f16* __restrict__ Wd1T,
                                             const f16* __restrict__ Wd2C,
                                             f16* __restrict__ Whi,
                                             f16* __restrict__ Wlo) {
  __shared__ f16 sA[128 * 40];
  __shared__ f16 sB[128 * 40];
  int m0 = blockIdx.x * 128, n0 = blockIdx.y * 128;
  int tid = threadIdx.x, w = tid >> 6, l = tid & 63;
  int wm = (w >> 1) * 64, wn = (w & 1) * 64;
  int lr = l & 15, lq = l >> 4;
  f32x4 acc[4][4] = {};
  for (int kt = 0; kt < 32; kt++) {
    int k0 = kt * 32;
    __syncthreads();
    int idx = tid;
#pragma unroll
    for (int rep = 0; rep < 2; rep++, idx += 256) {
      int r = idx >> 2, c = idx & 3;
      int ar = m0 + r; if (ar > 1055) ar = 1055;
      int br = n0 + r; if (br > 1055) br = 1055;
      *(uint4*)(&sA[r * 40 + c * 8]) =
          *(const uint4*)(Wd1T + (size_t)ar * 1088 + 64 + k0 + c * 8);
      *(uint4*)(&sB[r * 40 + c * 8]) =
          *(const uint4*)(Wd2C + (size_t)br * 1024 + k0 + c * 8);
    }
    __syncthreads();
    f16x8 a[4], bb[4];
#pragma unroll
    for (int i = 0; i < 4; i++) a[i] = *(const f16x8*)(&sA[(wm + i * 16 + lr) * 40 + lq * 8]);
#pragma unroll
    for (int j = 0; j < 4; j++) bb[j] = *(const f16x8*)(&sB[(wn + j * 16 + lr) * 40 + lq * 8]);
#pragma unroll
    for (int i = 0; i < 4; i++)
#pragma unroll
      for (int j = 0; j < 4; j++) acc[i][j] = MFMA16(a[i], bb[j], acc[i][j]);
  }
#pragma unroll
  for (int j = 0; j < 4; j++) {
    int n = n0 + wn + j * 16 + lr;
#pragma unroll
    for (int i = 0; i < 4; i++) {
#pragma unroll
      for (int rr = 0; rr < 4; rr++) {
        int m = m0 + wm + i * 16 + lq * 4 + rr;
        if (m < 1056 && n < 1056) {
          float v = acc[i][j][rr];
          f16 hi = (f16)v;
          Whi[(size_t)m * 1120 + 64 + n] = hi;
          Wlo[(size_t)m * 1120 + 64 + n] = (f16)(v - (float)hi);
        }
      }
    }
  }
}

// b'[j] = bd1[j] + sum_s bd2[s]*Wd1[64+s, j]; also fills ctrl part of Whi/Wlo
__global__ __launch_bounds__(256) void k_bprime(const f16* __restrict__ Wd1T,
                                                const float* __restrict__ bd1,
                                                const float* __restrict__ bd2,
                                                float* __restrict__ bp,
                                                f16* __restrict__ Whi,
                                                f16* __restrict__ Wlo) {
  __shared__ float red[4];
  int j = blockIdx.x;
  int tid = threadIdx.x, w = tid >> 6, l = tid & 63;
  float s = 0.f;
#pragma unroll
  for (int it = 0; it < 4; it++) {
    int k = it * 256 + tid;
    s += bd2[k] * (float)Wd1T[(size_t)j * 1088 + 64 + k];
  }
#pragma unroll
  for (int off = 32; off >= 1; off >>= 1) s += __shfl_down(s, off);
  if (l == 0) red[w] = s;
  __syncthreads();
  if (tid == 0) bp[j] = bd1[j] + red[0] + red[1] + red[2] + red[3];
  if (tid < 8) {
    *(uint4*)(Whi + (size_t)j * 1120 + tid * 8) =
        *(const uint4*)(Wd1T + (size_t)j * 1088 + tid * 8);
  } else if (tid < 16) {
    uint4 z = {};
    *(uint4*)(Wlo + (size_t)j * 1120 + (tid - 8) * 8) = z;
  }
}

// =============================== decoder ===============================
// Composed recurrence: h[t] = relu(c_t @ Wd1c + h[t-1] @ (M_hi + M_lo) + b').
// ONE rendezvous per step (h exchange only). Write-through stores land at the
// MALL (no release fence); per-line versioned u16 flags (producer owns its
// 64B line); wave 0 polls all 33 lines in parallel (one lane per line).
// M_hi fragments pinned in VGPRs, M_lo slice in LDS; h-row loads issued as
// one register batch (asm barrier) so the post-flag fetch is one MALL RT.
__device__ __forceinline__ void st_u64_wt(void* p, uint64_t v) {
  asm volatile("global_store_dwordx2 %0, %1, off sc0 sc1" :: "v"(p), "v"(v) : "memory");
}
__device__ __forceinline__ void st_u16_wt(void* p, unsigned v) {
  asm volatile("global_store_short %0, %1, off sc0 sc1" :: "v"(p), "v"(v) : "memory");
}
__device__ __forceinline__ unsigned ld_u16_wt(const void* p) {
  unsigned r;
  asm volatile("global_load_ushort %0, %1, off sc0 sc1\n\ts_waitcnt vmcnt(0)"
               : "=v"(r) : "v"(p) : "memory");
  return r;
}

// grid = 66: 2 groups (32 batch rows) x 33 col-slice blocks (32 h-cols each).
__global__ __launch_bounds__(256, 1) void k_decoder(
    const f16* __restrict__ ctrl, const f16* __restrict__ Whi,
    const f16* __restrict__ Wlo, const float* __restrict__ bp,
    const float* __restrict__ bd1, f16* __restrict__ hG,
    unsigned* __restrict__ flags) {
  extern __shared__ f16 sWlo[];   // [32][SWS]
  int blk = blockIdx.x;
  int g = blk / 33, j = blk % 33;
  int r0 = g * 32, n0 = j * 32;
  int tid = threadIdx.x, w = tid >> 6, l = tid & 63;
  int lr = l & 15, lq = l >> 4;
  int mt = w >> 1, nt = w & 1;

  // stage M_lo slice into LDS (k-contiguous rows)
  for (int idx = tid; idx < 32 * 140; idx += 256) {
    int c = idx / 140, q = idx % 140;
    *(uint4*)(&sWlo[c * SWS + q * 8]) = *(const uint4*)(Wlo + (size_t)(n0 + c) * 1120 + q * 8);
  }

  int wrow = nt * 16 + lr;           // this lane's weight column (output h col, local)
  int row_b = r0 + mt * 16 + lr;     // this lane's data row (global batch index)
  // M_hi fragments pinned in VGPRs (one-time global gather)
  const f16* whRow = Whi + (size_t)(n0 + wrow) * 1120;
  f16x8 wc0 = *(const f16x8*)(whRow + lq * 8);
  f16x8 wc1 = *(const f16x8*)(whRow + 32 + lq * 8);
  f16x8 wh[33];
#pragma unroll
  for (int i = 0; i < 33; i++)
    wh[i] = *(const f16x8*)(whRow + 64 + i * 32 + lq * 8);

  f32x4 b1v = *(const f32x4*)(bd1 + n0 + nt * 16 + lq * 4);
  f32x4 bpv = *(const f32x4*)(bp + n0 + nt * 16 + lq * 4);
  __syncthreads();

  char* fb = (char*)flags + (size_t)g * 8192;
  char* hf_me = fb + (size_t)j * 64;
  const char* hf_poll = fb + (size_t)l * 64;

  for (int t = 0; t < 256; t++) {
    f32x4 acch[4] = {}, accl[4] = {};
    {
      const f16* ctrlRow = ctrl + ((size_t)t * 64 + row_b) * 64;
      f16x8 a0 = *(const f16x8*)(ctrlRow + lq * 8);
      acch[0] = MFMA16(wc0, a0, acch[0]);
      f16x8 a1 = *(const f16x8*)(ctrlRow + 32 + lq * 8);
      acch[1] = MFMA16(wc1, a1, acch[1]);
    }
    if (t > 0) {
      if (w == 0) {
        unsigned need = (unsigned)t;
        for (;;) {
          unsigned v = need;
          if (l < 33) v = ld_u16_wt(hf_poll);
          if (__all((int)(v == need))) break;
        }
      }
      __syncthreads();
      const f16* hRow = hG + ((size_t)(t - 1) * 64 + row_b) * 1056;
      f16x8 av[33];
#pragma unroll
      for (int i = 0; i < 33; i++)
        av[i] = *(const f16x8*)(hRow + i * 32 + lq * 8);
      asm volatile("" ::: "memory");   // batch-issue all 33 loads before use
#pragma unroll
      for (int i = 0; i < 33; i++) {
        acch[i & 3] = MFMA16(wh[i], av[i], acch[i & 3]);
        f16x8 bl = *(const f16x8*)(&sWlo[wrow * SWS + 64 + i * 32 + lq * 8]);
        accl[i & 3] = MFMA16(bl, av[i], accl[i & 3]);
      }
    }
    f32x4 r1 = (acch[0] + acch[1]) + (acch[2] + acch[3]) +
               (accl[0] + accl[1]) + (accl[2] + accl[3]);
    f32x4 bv = (t == 0) ? b1v : bpv;
    f16x4 hv;
#pragma unroll
    for (int rr = 0; rr < 4; rr++) {
      float v = r1[rr] + bv[rr];
      hv[rr] = (f16)(v > 0.f ? v : 0.f);
    }
    st_u64_wt(hG + ((size_t)t * 64 + row_b) * 1056 + n0 + nt * 16 + lq * 4,
              __builtin_bit_cast(uint64_t, hv));
    asm volatile("s_waitcnt vmcnt(0)" ::: "memory");
    __syncthreads();
    if (tid == 0) st_u16_wt(hf_me, (unsigned)(t + 1));
  }
}

// =============================== final states GEMM ===============================
// states[m][n] = sum_k hG[m][k] * Wd2T[n][k] + bd2[n]   (m = t*64+b, no relu)
__global__ __launch_bounds__(256) void k_dec2(const f16* __restrict__ hG,
                                              const f16* __restrict__ Wd2T,
                                              const float* __restrict__ bd2,
                                              f16* __restrict__ states) {
  __shared__ f16 sA[128 * 40];
  __shared__ f16 sB[128 * 40];
  int m0 = blockIdx.x * 128, n0 = blockIdx.y * 128;
  int tid = threadIdx.x, w = tid >> 6, l = tid & 63;
  int wm = (w >> 1) * 64, wn = (w & 1) * 64;
  int lr = l & 15, lq = l >> 4;
  f32x4 acc[4][4] = {};
  for (int kt = 0; kt < 33; kt++) {
    int k0 = kt * 32;
    __syncthreads();
    int idx = tid;
#pragma unroll
    for (int rep = 0; rep < 2; rep++, idx += 256) {
      int r = idx >> 2, c = idx & 3;
      *(uint4*)(&sA[r * 40 + c * 8]) =
          *(const uint4*)(hG + (size_t)(m0 + r) * 1056 + k0 + c * 8);
      *(uint4*)(&sB[r * 40 + c * 8]) =
          *(const uint4*)(Wd2T + (size_t)(n0 + r) * 1056 + k0 + c * 8);
    }
    __syncthreads();
    f16x8 a[4], bb[4];
#pragma unroll
    for (int i = 0; i < 4; i++) a[i] = *(const f16x8*)(&sA[(wm + i * 16 + lr) * 40 + lq * 8]);
#pragma unroll
    for (int j = 0; j < 4; j++) bb[j] = *(const f16x8*)(&sB[(wn + j * 16 + lr) * 40 + lq * 8]);
#pragma unroll
    for (int i = 0; i < 4; i++)
#pragma unroll
      for (int j = 0; j < 4; j++) acc[i][j] = MFMA16(a[i], bb[j], acc[i][j]);
  }
#pragma unroll
  for (int j = 0; j < 4; j++) {
    int n = n0 + wn + j * 16 + lr;
    float bias = bd2[n];
#pragma unroll
    for (int i = 0; i < 4; i++) {
#pragma unroll
      for (int rr = 0; rr < 4; rr++) {
        int m = m0 + wm + i * 16 + lq * 4 + rr;
        states[(size_t)m * 1024 + n] = (f16)(acc[i][j][rr] + bias);
      }
    }
  }
}

// =============================== output ===============================
__global__ __launch_bounds__(256) void k_out(const f16* __restrict__ states,
                                             float* __restrict__ out) {
  __shared__ float tile[32][33];
  int b = blockIdx.z, t0 = blockIdx.x * 32, s0 = blockIdx.y * 32;
  int r = threadIdx.x >> 3, c4 = (threadIdx.x & 7) * 4;
  f16x4 v = *(const f16x4*)(states + ((size_t)(t0 + r) * 64 + b) * 1024 + s0 + c4);
  tile[r][c4 + 0] = (float)v[0]; tile[r][c4 + 1] = (float)v[1];
  tile[r][c4 + 2] = (float)v[2]; tile[r][c4 + 3] = (float)v[3];
  __syncthreads();
  float4 o;
  o.x = tile[c4 + 0][r]; o.y = tile[c4 + 1][r];
  o.z = tile[c4 + 2][r]; o.w = tile[c4 + 3][r];
  *(float4*)(out + ((size_t)b * 1024 + s0 + r) * 256 + t0 + c4) = o;
}

// =============================== launch ===============================

extern "C" void kernel_launch(void* const* d_in, const int* in_sizes, int n_in,
                              void* d_out, int out_size, void* d_ws, size_t ws_size,
                              hipStream_t stream) {
  const float* x   = (const float*)d_in[0];
  const float* We1 = (const float*)d_in[1];
  const float* be1 = (const float*)d_in[2];
  const float* We2 = (const float*)d_in[3];
  const float* be2 = (const float*)d_in[4];
  const float* Wd1 = (const float*)d_in[5];
  const float* bd1 = (const float*)d_in[6];
  const float* Wd2 = (const float*)d_in[7];
  const float* bd2 = (const float*)d_in[8];
  float* outp = (float*)d_out;

  if (ws_size < WS_NEED) return;
  char* ws = (char*)d_ws;
  f16* xT    = (f16*)(ws + OFF_XT);
  f16* We1T  = (f16*)(ws + OFF_WE1T);
  f16* We2T  = (f16*)(ws + OFF_WE2T);
  f16* Wd1T  = (f16*)(ws + OFF_WD1T);
  f16* Wd2T  = (f16*)(ws + OFF_WD2T);
  f16* Henc  = (f16*)(ws + OFF_HENC);
  f16* ctrl  = (f16*)(ws + OFF_CTRL);
  f16* st    = (f16*)(ws + OFF_ST);
  f16* hG    = Henc;                          // h exchange [256][64][1056] (HENC dead after enc2)
  f16* Whi   = (f16*)(ws + OFF_XT);           // composed weights (XT dead after enc1)
  f16* Wlo   = (f16*)(ws + OFF_XT + WHI_BYTES);
  f16* Wd2C  = (f16*)(ws + OFF_WE1T);         // f16 Wd2 copy (WE1T dead after enc1)
  unsigned* flags = (unsigned*)(ws + OFF_HG);
  float* bp  = (float*)(ws + OFF_BPRIME);

  (void)hipMemsetAsync(flags, 0, FLAG_BYTES, stream);
  k_zero_x0<<<64, 256, 0, stream>>>(xT);
  k_transpose_x<<<dim3(32, 8, 64), 256, 0, stream>>>(x, xT);
  k_transpose_w<<<dim3(64, 36), 256, 0, stream>>>(We1, We1T, 2048, 1056, 2048, 1152);
  k_transpose_w<<<dim3(36, 2), 256, 0, stream>>>(We2, We2T, 1056, 64, 1152, 64);
  k_transpose_w<<<dim3(34, 33), 256, 0, stream>>>(Wd1, Wd1T, 1088, 1056, 1088, 1056);
  k_transpose_w<<<dim3(33, 32), 256, 0, stream>>>(Wd2, Wd2T, 1056, 1024, 1056, 1024);
  k_enc1<<<dim3(128, 9), 256, 0, stream>>>(xT, We1T, be1, Henc);
  k_enc2<<<128, 256, 0, stream>>>(Henc, We2T, be2, ctrl);
  k_cast<<<528, 256, 0, stream>>>(Wd2, Wd2C);
  k_mkM<<<dim3(9, 9), 256, 0, stream>>>(Wd1T, Wd2C, Whi, Wlo);
  k_bprime<<<1056, 256, 0, stream>>>(Wd1T, bd1, bd2, bp, Whi, Wlo);
  (void)hipFuncSetAttribute((const void*)k_decoder, hipFuncAttributeMaxDynamicSharedMemorySize,
                            (int)DEC_LDS);
  k_decoder<<<66, 256, DEC_LDS, stream>>>(ctrl, Whi, Wlo, bp, bd1, hG, flags);
  k_dec2<<<dim3(128, 8), 256, 0, stream>>>(hG, Wd2T, bd2, st);
  k_out<<<dim3(8, 32, 64), 256, 0, stream>>>(st, outp);
}